// Round 4
// baseline (129.839 us; speedup 1.0000x reference)
//
#include <hip/hip_runtime.h>
#include <stdint.h>

#define NT 2048
#define DT 128

typedef __bf16 bf16x8 __attribute__((ext_vector_type(8)));
typedef __bf16 bf16x2 __attribute__((ext_vector_type(2)));
typedef float  f32x16 __attribute__((ext_vector_type(16)));

__device__ __forceinline__ float sigm(float x) {
    // sigmoid(x/sqrt(128)) = 1 / (1 + exp2(x * -log2(e)/sqrt(128)))
    return __builtin_amdgcn_rcpf(1.0f + __builtin_amdgcn_exp2f(x * -0.12753139620763842f));
}

// mfma_f32_32x32x16_bf16:
//  A: lane holds A[row=lane&31][k=(lane>>5)*8+j]
//  B: lane holds B[k=(lane>>5)*8+j][col=lane&31]
//  C/D: col=lane&31, row=(reg&3)+8*(reg>>2)+4*(lane>>5)
//
// Wave (wm, wv): m-col = 32*wm, v-half = 64*wv. Each wave computes the FULL
// S(64n x 32m) per n-chunk (duplicated across the wv pair) so the C->B
// transform of S stays in-register (one l^32 shuffle), eliminating the Ss
// LDS round-trip and the second barrier. Qs/Vs double-buffered -> exactly
// one __syncthreads per iteration; prefetch is consumed before the barrier
// so the compiler's vmcnt(0) drain at s_barrier costs nothing.
__global__ __launch_bounds__(512, 4)
void sig_attn(const float* __restrict__ Q, const float* __restrict__ K,
              const float* __restrict__ V, float* __restrict__ out)
{
    __shared__ __align__(16) __bf16 Qs[2][64 * 128];   // [n][d] bf16, 16B granules xor'd by n&15
    __shared__ __align__(16) __bf16 Vs[2][128 * 64];   // [v][n] bf16, granules xor'd by v&7

    const int t   = threadIdx.x;
    const int w   = t >> 6;      // wave 0..7
    const int l   = t & 63;
    const int lq  = l >> 5;
    const int l31 = l & 31;
    const int lx  = l ^ 32;      // shuffle partner (other 32-lane half)
    const int wm  = w & 3;       // 32-wide m-column
    const int wv  = w >> 2;      // 64-wide v-half

    const int bid    = blockIdx.x;
    const int b      = bid & 7;          // XCD-pinned batch
    const int mt     = (bid >> 3) & 15;
    const int ns     = bid >> 7;         // 0..3 n-split
    const int m_blk  = mt * 128;
    const int n_base = ns * 512;

    const float* Qb = Q + (size_t)b * DT * NT;
    const float* Kb = K + (size_t)b * DT * NT;
    const float* Vb = V + (size_t)b * DT * NT;
    float*       Ob = out + (size_t)b * DT * NT;

    const int mrow = 32 * wm + l31;

    // ---- prefetch chunk 0 (issued first so it overlaps the K preload)
    float  qp[16];
    float4 vp[4];
    {
        #pragma unroll
        for (int r = 0; r < 2; ++r)
            #pragma unroll
            for (int j = 0; j < 8; ++j)
                qp[r * 8 + j] = Qb[(size_t)(64 * r + 8 * w + j) * NT + n_base + l];
        const float* vb = Vb + (size_t)(t >> 2) * NT + n_base + 8 * (t & 3);
        vp[0] = *(const float4*)(vb);
        vp[1] = *(const float4*)(vb + 4);
        vp[2] = *(const float4*)(vb + 32);
        vp[3] = *(const float4*)(vb + 36);
    }

    // ---- K -> register-resident B-frags: kf[k][j] = K[d=16k+8lq+j][m_blk+mrow]
    bf16x8 kf[8];
    #pragma unroll
    for (int half = 0; half < 2; ++half) {
        float tmp[4][8];
        #pragma unroll
        for (int k2 = 0; k2 < 4; ++k2)
            #pragma unroll
            for (int j = 0; j < 8; ++j)
                tmp[k2][j] = Kb[(size_t)((half * 4 + k2) * 16 + lq * 8 + j) * NT + m_blk + mrow];
        #pragma unroll
        for (int k2 = 0; k2 < 4; ++k2) {
            bf16x8 f;
            #pragma unroll
            for (int j = 0; j < 8; ++j) f[j] = (__bf16)tmp[k2][j];
            kf[half * 4 + k2] = f;
        }
    }

    f32x16 oacc[2];
    #pragma unroll
    for (int tv = 0; tv < 2; ++tv)
        #pragma unroll
        for (int r = 0; r < 16; ++r)
            oacc[tv][r] = 0.0f;

    for (int it = 0; it < 8; ++it) {
        __bf16* Qbuf = Qs[it & 1];
        __bf16* Vbuf = Vs[it & 1];

        // ---- stores of prefetched chunk (Q: 2x b128; V: 2x b128)
        #pragma unroll
        for (int r = 0; r < 2; ++r) {
            bf16x8 pk;
            #pragma unroll
            for (int j = 0; j < 8; ++j) pk[j] = (__bf16)qp[r * 8 + j];
            *(bf16x8*)&Qbuf[l * 128 + (((8 * r + w) ^ (l & 15)) * 8)] = pk;
        }
        {
            const int v = t >> 2;
            #pragma unroll
            for (int u = 0; u < 2; ++u) {
                const int g = (t & 3) + 4 * u;
                const float* s = (const float*)&vp[2 * u];
                bf16x8 pk;
                #pragma unroll
                for (int j = 0; j < 8; ++j) pk[j] = (__bf16)s[j];
                *(bf16x8*)&Vbuf[v * 64 + ((g ^ (v & 7)) * 8)] = pk;
            }
        }
        __syncthreads();   // the ONLY barrier this iteration

        // ---- prefetch chunk it+1 (consumed by next iter's stores, i.e. fully
        //      before the next barrier -> no drain stall at s_barrier)
        {
            const int n0 = n_base + ((it + 1) & 7) * 64;
            #pragma unroll
            for (int r = 0; r < 2; ++r)
                #pragma unroll
                for (int j = 0; j < 8; ++j)
                    qp[r * 8 + j] = Qb[(size_t)(64 * r + 8 * w + j) * NT + n0 + l];
            const float* vb = Vb + (size_t)(t >> 2) * NT + n0 + 8 * (t & 3);
            vp[0] = *(const float4*)(vb);
            vp[1] = *(const float4*)(vb + 4);
            vp[2] = *(const float4*)(vb + 32);
            vp[3] = *(const float4*)(vb + 36);
        }

        // ---- two 32-n halves, fully per-wave (no cross-wave data flow)
        #pragma unroll
        for (int h = 0; h < 2; ++h) {
            // GEMM1: sacc = S[32h + rowmap][m-col]
            f32x16 sacc;
            #pragma unroll
            for (int r = 0; r < 16; ++r) sacc[r] = 0.0f;
            const int nrow = 32 * h + l31;
            #pragma unroll
            for (int k = 0; k < 8; ++k) {
                const bf16x8 af =
                    *(const bf16x8*)&Qbuf[nrow * 128 + (((2 * k + lq) ^ (nrow & 15)) * 8)];
                sacc = __builtin_amdgcn_mfma_f32_32x32x16_bf16(af, kf[k], sacc, 0, 0, 0);
            }

            // sigmoid -> packed bf16 pairs P[i] = rows {row(2i),row(2i+1)} of col m
            int Pi[8];
            #pragma unroll
            for (int i = 0; i < 8; ++i) {
                bf16x2 p;
                p[0] = (__bf16)sigm(sacc[2 * i]);
                p[1] = (__bf16)sigm(sacc[2 * i + 1]);
                Pi[i] = __builtin_bit_cast(int, p);
            }

            // GEMM2: C-layout -> B-layout via one l^32 exchange per pair
            #pragma unroll
            for (int s = 0; s < 2; ++s) {
                const int x  = lq ? Pi[4 * s + 0] : Pi[4 * s + 2];
                const int y  = lq ? Pi[4 * s + 1] : Pi[4 * s + 3];
                const int xs = __shfl(x, lx, 64);
                const int ys = __shfl(y, lx, 64);
                union { int i[4]; bf16x8 v; } bf;
                bf.i[0] = lq ? xs : Pi[4 * s + 0];
                bf.i[1] = lq ? ys : Pi[4 * s + 1];
                bf.i[2] = lq ? Pi[4 * s + 2] : xs;
                bf.i[3] = lq ? Pi[4 * s + 3] : ys;

                const int sl  = ((4 * h + 2 * s + lq) ^ (l31 & 7)) * 8;
                const bf16x8 av0 = *(const bf16x8*)&Vbuf[(64 * wv + l31) * 64 + sl];
                const bf16x8 av1 = *(const bf16x8*)&Vbuf[(64 * wv + 32 + l31) * 64 + sl];
                oacc[0] = __builtin_amdgcn_mfma_f32_32x32x16_bf16(av0, bf.v, oacc[0], 0, 0, 0);
                oacc[1] = __builtin_amdgcn_mfma_f32_32x32x16_bf16(av1, bf.v, oacc[1], 0, 0, 0);
            }
        }
    }

    // ---- epilogue: merge 4 n-split partials (atomics measured cheap in R2->R3)
    #pragma unroll
    for (int tv = 0; tv < 2; ++tv) {
        #pragma unroll
        for (int r = 0; r < 16; ++r) {
            const int v = 64 * wv + 32 * tv + (r & 3) + 8 * (r >> 2) + 4 * lq;
            atomicAdd(&Ob[(size_t)v * NT + m_blk + mrow], oacc[tv][r]);
        }
    }
}

extern "C" void kernel_launch(void* const* d_in, const int* in_sizes, int n_in,
                              void* d_out, int out_size, void* d_ws, size_t ws_size,
                              hipStream_t stream) {
    (void)in_sizes; (void)n_in; (void)d_ws; (void)ws_size;
    const float* Q = (const float*)d_in[0];
    const float* K = (const float*)d_in[1];
    const float* V = (const float*)d_in[2];
    float* O = (float*)d_out;
    // harness re-poisons d_out with 0xAA before every launch; atomics need zeros
    hipMemsetAsync(d_out, 0, (size_t)out_size * sizeof(float), stream);
    sig_attn<<<dim3(512), dim3(512), 0, stream>>>(Q, K, V, O);
}